// Round 2
// baseline (121.598 us; speedup 1.0000x reference)
//
#include <hip/hip_runtime.h>

// Problem constants
static constexpr int NQ    = 12;
static constexpr int DEPTH = 4;
static constexpr int LAT   = 512;
static constexpr int FAST  = DEPTH * NQ;   // 48
static constexpr float DECAY = 0.9f;
static constexpr int P     = 68;           // row pitch (floats): 272 B, 16B-aligned

using v2f = __attribute__((ext_vector_type(2))) float;

// r16 KEY CHANGE: the two LDS transposes per layer are replaced by ONE b128
// round-trip per layer + in-register lane exchanges (DPP / ds_swizzle).
//
// Derivation (matches the r13-verified A0 = gray6(lane) addressing):
//   amp index i = (lane<<6) | reg;  wire w <-> i-bit (11-w).
//   CNOT chain sigma^-1(j): bit_p = j_p ^ j_{p+1} (p=0..10), bit11 = j11
//     => src_lane = G6(jl),  src_reg = G6(jr) ^ (jl0<<5)   [jl0 = lane bit0]
//   Keep registers GRAY-RELABELED: invariant t[k] = amp(G6^-1(k)).
//   - write canonical: X[lane][c] = t[G6(c)]           (16 x b128)
//   - read  self:  w[k] = X[G6(lane)][k ^ (jl0<<5)]    (16 x b128)
//     then amp_mid(jr) = w[G6(jr)]  -- the jl0 offsets CANCEL, invariant kept.
//   - wire0 partner (lane bit5): row G6(lane)^48, same cols (16 x b128);
//     t[k] = c0*w[k] + ss0*p[k] elementwise (ss0 = lane&32 ? +s : -s).
//   - lane-bit wires 4..0: partner via xor16=ds_swizzle(0x401F),
//     xor8=DPP row_ror:8, xor4=DPP(xor3)+DPP(xor7), xor2/xor1=quad_perm.
//     All exchange patterns are involutions (direction-proof).
//   - reg-bit wires: butterfly pairs k, k^M with M = G6(bit) in
//     {48,24,12,6,3,1}; 0-side = parity(k>>b)==0 (compile-time).
// Result: 1 LDS round-trip/layer (b128 both sides), rest is a pure VALU
// stream -> the r14/r15 latency convoy (writes -> all-to-all reads ->
// lgkmcnt(15)-clamped drain, x2/layer) disappears.
// 2 elements per wave (r14 base): shares W_enc/W_upd loads, and B's single
// round-trip hides under A's ~1500-cycle wire math.

__device__ __forceinline__ constexpr int G6(int x)  { return (x ^ (x >> 1)) & 63; }
__device__ __forceinline__ constexpr int GINV(int x){ int y = x; y ^= y >> 1; y ^= y >> 2; y ^= y >> 4; return y & 63; }

template<int CTRL>
__device__ __forceinline__ float dppf(float x){
    return __int_as_float(__builtin_amdgcn_mov_dpp(__float_as_int(x), CTRL, 0xF, 0xF, false));
}
template<int B> __device__ __forceinline__ float lexch(float x);
template<> __device__ __forceinline__ float lexch<0>(float x){ return dppf<0xB1>(x); }   // lane^1: quad_perm[1,0,3,2]
template<> __device__ __forceinline__ float lexch<1>(float x){ return dppf<0x4E>(x); }   // lane^2: quad_perm[2,3,0,1]
template<> __device__ __forceinline__ float lexch<2>(float x){ return dppf<0x141>(dppf<0x1B>(x)); } // lane^4 = xor7 o xor3
template<> __device__ __forceinline__ float lexch<3>(float x){ return dppf<0x128>(x); }  // lane^8: row_ror:8
template<> __device__ __forceinline__ float lexch<4>(float x){                           // lane^16
    return __int_as_float(__builtin_amdgcn_ds_swizzle(__float_as_int(x), 0x401F));
}

// RY on a lane-bit wire: new = c*t + ss*partner, ss = (+s if bit set else -s)
template<int B>
__device__ __forceinline__ void lanewire(float (&t)[64], float c, float ss){
    #pragma unroll
    for (int k = 0; k < 64; k++){
        float p = lexch<B>(t[k]);
        t[k] = __builtin_fmaf(c, t[k], ss * p);
    }
}

// RY on a reg-bit wire in gray space: pairs (k, k^M), M = G6(1<<B)
template<int B>
__device__ __forceinline__ void regwire(float (&t)[64], float c, float s){
    constexpr int M = (B == 0) ? 1 : ((1 << B) | (1 << (B - 1)));
    #pragma unroll
    for (int k = 0; k < 64; k++){
        if (__builtin_parity((unsigned)(k >> B)) == 0){   // amp bit B of GINV(k) == 0
            float a = t[k], b = t[k ^ M];
            t[k]     = c * a - s * b;
            t[k ^ M] = s * a + c * b;
        }
    }
}

// canonical write: X[lane][c] = amp(c) = t[G6(c)]
__device__ __forceinline__ void stageW(const float (&t)[64], float* X, int wbase){
    #pragma unroll
    for (int m = 0; m < 16; m++)
        *(float4*)&X[wbase + 4*m] =
            (float4){ t[G6(4*m+0)], t[G6(4*m+1)], t[G6(4*m+2)], t[G6(4*m+3)] };
}

// sigma-folded read (self + wire0 partner) + wire0 butterfly, chunked b128
__device__ __forceinline__ void stageR0(float (&t)[64], const float* X, int rs, int rp, int off,
                                        float c0, float ss0){
    #pragma unroll
    for (int m = 0; m < 16; m++){
        int col = (4*m) ^ off;                       // off = (lane&1)*32, 16B-aligned xor
        float4 a = *(const float4*)&X[rs + col];     // row G6(lane)
        float4 b = *(const float4*)&X[rp + col];     // row G6(lane)^48  (partner lane^32)
        t[4*m+0] = __builtin_fmaf(c0, a.x, ss0 * b.x);
        t[4*m+1] = __builtin_fmaf(c0, a.y, ss0 * b.y);
        t[4*m+2] = __builtin_fmaf(c0, a.z, ss0 * b.z);
        t[4*m+3] = __builtin_fmaf(c0, a.w, ss0 * b.w);
    }
}

__device__ __forceinline__ void wiresLane(float (&t)[64], const v2f* c, int lane){
    { v2f cs = c[1]; lanewire<4>(t, cs.x, (lane & 16) ? cs.y : -cs.y); }  // wire1 <-> lane bit4
    { v2f cs = c[2]; lanewire<3>(t, cs.x, (lane &  8) ? cs.y : -cs.y); }
    { v2f cs = c[3]; lanewire<2>(t, cs.x, (lane &  4) ? cs.y : -cs.y); }
    { v2f cs = c[4]; lanewire<1>(t, cs.x, (lane &  2) ? cs.y : -cs.y); }
    { v2f cs = c[5]; lanewire<0>(t, cs.x, (lane &  1) ? cs.y : -cs.y); }  // wire5 <-> lane bit0
}
__device__ __forceinline__ void wiresReg(float (&t)[64], const v2f* c){
    { v2f cs = c[6];  regwire<5>(t, cs.x, cs.y); }   // wire6  <-> reg bit5, M=48
    { v2f cs = c[7];  regwire<4>(t, cs.x, cs.y); }   // M=24
    { v2f cs = c[8];  regwire<3>(t, cs.x, cs.y); }   // M=12
    { v2f cs = c[9];  regwire<2>(t, cs.x, cs.y); }   // M=6
    { v2f cs = c[10]; regwire<1>(t, cs.x, cs.y); }   // M=3
    { v2f cs = c[11]; regwire<0>(t, cs.x, cs.y); }   // wire11 <-> reg bit0, M=1
}

// closed-form product state from the 12 initial RYs (verified r2-r13)
__device__ __forceinline__ void init_state(float (&v)[64], const float (&xa)[NQ], int lane) {
    float g0[NQ], g1[NQ];
    #pragma unroll
    for (int w = 0; w < NQ; w++) {
        float hh = 0.5f * xa[w];
        float c = __cosf(hh), s = __sinf(hh);
        g0[w] = (c - s) * 0.70710678118654752f;
        g1[w] = (c + s) * 0.70710678118654752f;
    }
    float L = 1.0f;
    #pragma unroll
    for (int w = 0; w < 6; w++)
        L *= ((lane >> (5 - w)) & 1) ? g1[w] : g0[w];
    v[0] = L;
    #pragma unroll
    for (int w = 6; w < NQ; w++) {
        const int S = 1 << (11 - w);
        #pragma unroll
        for (int r = 0; r < 64; r += 2 * S) {
            v[r + S] = v[r] * g1[w];
            v[r]     = v[r] * g0[w];
        }
    }
}

__global__ __launch_bounds__(64, 1)
void fwp_kernel(const float* __restrict__ x_t,
                const float* __restrict__ fast_prev,
                const float* __restrict__ W_enc,
                const float* __restrict__ b_enc,
                const float* __restrict__ W_upd,
                const float* __restrict__ b_upd,
                const float* __restrict__ W_ro,
                const float* __restrict__ b_ro,
                float* __restrict__ out_y,
                float* __restrict__ out_fast) {
    const int lane = threadIdx.x;          // block = one wave
    const int eA   = 2 * blockIdx.x;
    const int eB   = eA + 1;

    __shared__ __align__(16) float XA[64 * P];   // 17408 B
    __shared__ __align__(16) float XB[64 * P];   // 17408 B
    __shared__ __align__(8)  v2f   csA[FAST], csB[FAST];

    float* latA = XA;   // latents carved from circuit buffers (dead later)
    float* latB = XB;

    // ---- x rows (wave-uniform scalar loads, verified r7) ----
    float xaA[NQ], xaB[NQ];
    #pragma unroll
    for (int k = 0; k < NQ; k++) {
        xaA[k] = x_t[eA * NQ + k];
        xaB[k] = x_t[eB * NQ + k];
    }

    // ---- Phase A: lane owns latents j = 8*lane..8*lane+7 (verified r13) ----
    {
        const float4* we = (const float4*)(W_enc + lane * 8 * NQ);  // 8 rows, 384 B
        float4 be0 = *(const float4*)&b_enc[8 * lane];
        float4 be1 = *(const float4*)&b_enc[8 * lane + 4];
        float be[8] = {be0.x, be0.y, be0.z, be0.w, be1.x, be1.y, be1.z, be1.w};
        float lA[8], lB[8];
        #pragma unroll
        for (int t = 0; t < 8; t++) {
            float4 a0 = we[3 * t], a1 = we[3 * t + 1], a2 = we[3 * t + 2];
            float sA = be[t]
                + a0.x * xaA[0] + a0.y * xaA[1] + a0.z * xaA[2]  + a0.w * xaA[3]
                + a1.x * xaA[4] + a1.y * xaA[5] + a1.z * xaA[6]  + a1.w * xaA[7]
                + a2.x * xaA[8] + a2.y * xaA[9] + a2.z * xaA[10] + a2.w * xaA[11];
            float sB = be[t]
                + a0.x * xaB[0] + a0.y * xaB[1] + a0.z * xaB[2]  + a0.w * xaB[3]
                + a1.x * xaB[4] + a1.y * xaB[5] + a1.z * xaB[6]  + a1.w * xaB[7]
                + a2.x * xaB[8] + a2.y * xaB[9] + a2.z * xaB[10] + a2.w * xaB[11];
            lA[t] = tanhf(sA);
            lB[t] = tanhf(sB);
        }
        *(float4*)&latA[8 * lane]     = (float4){lA[0], lA[1], lA[2], lA[3]};
        *(float4*)&latA[8 * lane + 4] = (float4){lA[4], lA[5], lA[6], lA[7]};
        *(float4*)&latB[8 * lane]     = (float4){lB[0], lB[1], lB[2], lB[3]};
        *(float4*)&latB[8 * lane + 4] = (float4){lB[4], lB[5], lB[6], lB[7]};
    }

    // ---- Phase B: 48 angles per element; W_upd row loaded once ----
    if (lane < FAST) {
        const float4* wr = (const float4*)(W_upd + lane * LAT);
        const float4* la = (const float4*)(latA);
        const float4* lb = (const float4*)(latB);
        float base = b_upd[lane];
        float sA = base, sB = base;
        #pragma unroll 8
        for (int j = 0; j < LAT / 4; j++) {
            float4 w4 = wr[j];
            float4 a4 = la[j];   // uniform -> broadcast
            float4 b4 = lb[j];
            sA += w4.x * a4.x + w4.y * a4.y + w4.z * a4.z + w4.w * a4.w;
            sB += w4.x * b4.x + w4.y * b4.y + w4.z * b4.z + w4.w * b4.w;
        }
        float angA = DECAY * fast_prev[eA * FAST + lane] + sA;
        float angB = DECAY * fast_prev[eB * FAST + lane] + sB;
        out_fast[eA * FAST + lane] = angA;
        out_fast[eB * FAST + lane] = angB;
        csA[lane] = (v2f){__cosf(0.5f * angA), __sinf(0.5f * angA)};
        csB[lane] = (v2f){__cosf(0.5f * angB), __sinf(0.5f * angB)};
    }

    // ---- product states, pre-grayed: t[k] = amp(GINV(k)) ----
    float tmp[64], tA[64], tB[64];
    init_state(tmp, xaA, lane);
    #pragma unroll
    for (int k = 0; k < 64; k++) tA[k] = tmp[GINV(k)];
    init_state(tmp, xaB, lane);
    #pragma unroll
    for (int k = 0; k < 64; k++) tB[k] = tmp[GINV(k)];

    const int wbase = lane * P;
    const int gl    = (lane ^ (lane >> 1)) & 63;   // G6(lane)
    const int rs    = gl * P;
    const int rp    = (gl ^ 48) * P;               // partner row (lane^32)
    const int off   = (lane & 1) * 32;             // jl0 column offset (cancels in gray space)

    // ---- 4 layers; one b128 round-trip each, rest pure VALU/DPP stream ----
    #pragma unroll 1
    for (int layer = 0; layer < DEPTH; layer++) {
        const v2f* cA = csA + layer * NQ;
        const v2f* cB = csB + layer * NQ;
        v2f a0 = cA[0], b0 = cB[0];
        float ssA0 = (lane & 32) ? a0.y : -a0.y;
        float ssB0 = (lane & 32) ? b0.y : -b0.y;

        stageW(tA, XA, wbase);
        stageR0(tA, XA, rs, rp, off, a0.x, ssA0);
        stageW(tB, XB, wbase);            // B's DS in flight under A's wire math
        wiresLane(tA, cA, lane);
        stageR0(tB, XB, rs, rp, off, b0.x, ssB0);
        wiresReg(tA, cA);                 // covers B's read latency
        wiresLane(tB, cB, lane);
        wiresReg(tB, cB);
    }

    // ---- Z expectations folded into readout; amp(r) = t[G6(r)] ----
    float wro[NQ];
    #pragma unroll
    for (int w = 0; w < NQ; w++) wro[w] = W_ro[w];
    float sl = 0.0f;
    #pragma unroll
    for (int w = 0; w < 6; w++)
        sl += ((lane >> (5 - w)) & 1) ? -wro[w] : wro[w];

    float totA = 0.0f, pwA[6] = {0,0,0,0,0,0};
    float totB = 0.0f, pwB[6] = {0,0,0,0,0,0};
    #pragma unroll
    for (int r = 0; r < 64; r++) {
        float aA = tA[G6(r)], aB = tB[G6(r)];
        float pA = aA * aA;
        float pB = aB * aB;
        totA += pA;  totB += pB;
        pwA[0] += (r & 32) ? -pA : pA;  pwB[0] += (r & 32) ? -pB : pB;
        pwA[1] += (r & 16) ? -pA : pA;  pwB[1] += (r & 16) ? -pB : pB;
        pwA[2] += (r & 8)  ? -pA : pA;  pwB[2] += (r & 8)  ? -pB : pB;
        pwA[3] += (r & 4)  ? -pA : pA;  pwB[3] += (r & 4)  ? -pB : pB;
        pwA[4] += (r & 2)  ? -pA : pA;  pwB[4] += (r & 2)  ? -pB : pB;
        pwA[5] += (r & 1)  ? -pA : pA;  pwB[5] += (r & 1)  ? -pB : pB;
    }
    float yA = sl * totA, yB = sl * totB;
    #pragma unroll
    for (int k = 0; k < 6; k++) {
        yA += wro[6 + k] * pwA[k];
        yB += wro[6 + k] * pwB[k];
    }
    #pragma unroll
    for (int m = 32; m >= 1; m >>= 1) {
        yA += __shfl_xor(yA, m, 64);
        yB += __shfl_xor(yB, m, 64);
    }
    if (lane == 0) {
        float br = b_ro[0];
        out_y[eA] = yA + br;
        out_y[eB] = yB + br;
    }
}

extern "C" void kernel_launch(void* const* d_in, const int* in_sizes, int n_in,
                              void* d_out, int out_size, void* d_ws, size_t ws_size,
                              hipStream_t stream) {
    const float* x_t       = (const float*)d_in[0];
    const float* fast_prev = (const float*)d_in[1];
    const float* W_enc     = (const float*)d_in[2];
    const float* b_enc     = (const float*)d_in[3];
    const float* W_upd     = (const float*)d_in[4];
    const float* b_upd     = (const float*)d_in[5];
    const float* W_ro      = (const float*)d_in[6];
    const float* b_ro      = (const float*)d_in[7];
    float* out = (float*)d_out;

    // 1024 blocks x 1 wave, 2 batch elements per wave
    fwp_kernel<<<1024, 64, 0, stream>>>(x_t, fast_prev, W_enc, b_enc,
                                        W_upd, b_upd, W_ro, b_ro,
                                        out /*y*/, out + 2048 /*fast_next*/);
}

// Round 3
// 117.305 us; speedup vs baseline: 1.0366x; 1.0366x over previous
//
#include <hip/hip_runtime.h>

// Problem constants
static constexpr int NQ    = 12;
static constexpr int DEPTH = 4;
static constexpr int LAT   = 512;
static constexpr int FAST  = DEPTH * NQ;   // 48
static constexpr float DECAY = 0.9f;
static constexpr int PPF   = 132;  // floats per LDS row = 66 v2f = 528 B; bank-step 4 (same class as proven 272B pitch)

using v2f = __attribute__((ext_vector_type(2))) float;

// r17: elements A,B packed as v2f halves; ONE sigma round-trip per layer.
//   amp index i = (lane<<6)|r. sigma^-1((h<<6)|l) = (G6(h)<<6) | (G6(l) ^ (h0*32))
//   [verified r13/r16 on HW]. Canonical labeling u[r] = amp(r) throughout:
//   - stage write: X[lane][c] = u[c]  (32 straight b128, zero marshal)
//   - read self row G6(lane), partner row G6(lane)^48; the per-lane ^32
//     column offset (off2 = (lane&1)*64 floats) folds into TWO base
//     pointers, so all register indices are compile-time: u[r] =
//     cc0*w'[G6(r)] + ss0*p'[G6(r)]  (wire0 fused; G6 preserves 4-blocks:
//     source block of output block b is G4(b)=b^(b>>1), in-block map
//     {0,1,3,2}/{2,3,1,0} by b&1).
//   - wires 1..5 (lane bits 4..0): xor16 ds_swizzle 0x401F, xor8 row_ror:8,
//     xor4 = half_mirror o quad_perm[3,2,1,0], xor2/xor1 quad_perm
//     [all verified r16], applied per v2f component.
//   - wires 6..11 (amp bits 5..0): clean power-of-2 register butterflies
//     [r14-verified shape], on v2f -> packed-f32 math covers A and B.
// Per wave-layer: 96 b128 + 128 swizzle DS ops (vs r14's 320 mixed, and
// 1 round-trip instead of 2); all wire math is 2-elements-per-instr.

__device__ __forceinline__ constexpr int G6(int x)  { return (x ^ (x >> 1)) & 63; }

template<int CTRL>
__device__ __forceinline__ float dppf(float x){
    return __int_as_float(__builtin_amdgcn_mov_dpp(__float_as_int(x), CTRL, 0xF, 0xF, false));
}
template<int B> __device__ __forceinline__ float lexch(float x);
template<> __device__ __forceinline__ float lexch<0>(float x){ return dppf<0xB1>(x); }   // lane^1
template<> __device__ __forceinline__ float lexch<1>(float x){ return dppf<0x4E>(x); }   // lane^2
template<> __device__ __forceinline__ float lexch<2>(float x){ return dppf<0x141>(dppf<0x1B>(x)); } // lane^4
template<> __device__ __forceinline__ float lexch<3>(float x){ return dppf<0x128>(x); }  // lane^8
template<> __device__ __forceinline__ float lexch<4>(float x){                           // lane^16
    return __int_as_float(__builtin_amdgcn_ds_swizzle(__float_as_int(x), 0x401F));
}
template<int B> __device__ __forceinline__ v2f lexch2(v2f v){
    return (v2f){ lexch<B>(v.x), lexch<B>(v.y) };
}

// RY on a lane-bit wire, both elements: u = cc*u + ssv*partner
template<int B>
__device__ __forceinline__ void lanewire2(v2f (&u)[64], v2f cc, v2f ssv){
    #pragma unroll
    for (int k = 0; k < 64; k++){
        v2f p = lexch2<B>(u[k]);
        u[k] = cc * u[k] + ssv * p;
    }
}

// RY on an amp-register bit, both elements: textbook butterfly
template<int BIT>
__device__ __forceinline__ void regwire2(v2f (&u)[64], v2f cc, v2f ss){
    constexpr int M = 1 << BIT;
    #pragma unroll
    for (int r = 0; r < 64; r++){
        if (!(r & M)){
            v2f a = u[r], b = u[r ^ M];
            u[r]     = cc * a - ss * b;
            u[r ^ M] = ss * a + cc * b;
        }
    }
}

__global__ __launch_bounds__(64, 1)
void fwp_kernel(const float* __restrict__ x_t,
                const float* __restrict__ fast_prev,
                const float* __restrict__ W_enc,
                const float* __restrict__ b_enc,
                const float* __restrict__ W_upd,
                const float* __restrict__ b_upd,
                const float* __restrict__ W_ro,
                const float* __restrict__ b_ro,
                float* __restrict__ out_y,
                float* __restrict__ out_fast) {
    const int lane = threadIdx.x;          // block = one wave
    const int eA   = 2 * blockIdx.x;
    const int eB   = eA + 1;

    __shared__ __align__(16) float Xs[64 * PPF];      // 33792 B (paired state)
    __shared__ __align__(8)  v2f CC[FAST], SS[FAST];  // zipped (A,B) angles

    float* latA = Xs;         // latents carved from circuit buffer (dead later)
    float* latB = Xs + LAT;

    // ---- x rows (wave-uniform scalar loads, verified r7) ----
    float xaA[NQ], xaB[NQ];
    #pragma unroll
    for (int k = 0; k < NQ; k++) {
        xaA[k] = x_t[eA * NQ + k];
        xaB[k] = x_t[eB * NQ + k];
    }

    // ---- Phase A: lane owns latents j = 8*lane..8*lane+7 (verified r13) ----
    {
        const float4* we = (const float4*)(W_enc + lane * 8 * NQ);  // 8 rows, 384 B
        float4 be0 = *(const float4*)&b_enc[8 * lane];
        float4 be1 = *(const float4*)&b_enc[8 * lane + 4];
        float be[8] = {be0.x, be0.y, be0.z, be0.w, be1.x, be1.y, be1.z, be1.w};
        float lA[8], lB[8];
        #pragma unroll
        for (int t = 0; t < 8; t++) {
            float4 a0 = we[3 * t], a1 = we[3 * t + 1], a2 = we[3 * t + 2];
            float sA = be[t]
                + a0.x * xaA[0] + a0.y * xaA[1] + a0.z * xaA[2]  + a0.w * xaA[3]
                + a1.x * xaA[4] + a1.y * xaA[5] + a1.z * xaA[6]  + a1.w * xaA[7]
                + a2.x * xaA[8] + a2.y * xaA[9] + a2.z * xaA[10] + a2.w * xaA[11];
            float sB = be[t]
                + a0.x * xaB[0] + a0.y * xaB[1] + a0.z * xaB[2]  + a0.w * xaB[3]
                + a1.x * xaB[4] + a1.y * xaB[5] + a1.z * xaB[6]  + a1.w * xaB[7]
                + a2.x * xaB[8] + a2.y * xaB[9] + a2.z * xaB[10] + a2.w * xaB[11];
            lA[t] = tanhf(sA);
            lB[t] = tanhf(sB);
        }
        *(float4*)&latA[8 * lane]     = (float4){lA[0], lA[1], lA[2], lA[3]};
        *(float4*)&latA[8 * lane + 4] = (float4){lA[4], lA[5], lA[6], lA[7]};
        *(float4*)&latB[8 * lane]     = (float4){lB[0], lB[1], lB[2], lB[3]};
        *(float4*)&latB[8 * lane + 4] = (float4){lB[4], lB[5], lB[6], lB[7]};
    }

    // ---- Phase B: 48 angles per element; W_upd row loaded once ----
    if (lane < FAST) {
        const float4* wr = (const float4*)(W_upd + lane * LAT);
        const float4* la = (const float4*)(latA);
        const float4* lb = (const float4*)(latB);
        float base = b_upd[lane];
        float sA = base, sB = base;
        #pragma unroll 8
        for (int j = 0; j < LAT / 4; j++) {
            float4 w4 = wr[j];
            float4 a4 = la[j];   // uniform -> broadcast
            float4 b4 = lb[j];
            sA += w4.x * a4.x + w4.y * a4.y + w4.z * a4.z + w4.w * a4.w;
            sB += w4.x * b4.x + w4.y * b4.y + w4.z * b4.z + w4.w * b4.w;
        }
        float angA = DECAY * fast_prev[eA * FAST + lane] + sA;
        float angB = DECAY * fast_prev[eB * FAST + lane] + sB;
        out_fast[eA * FAST + lane] = angA;
        out_fast[eB * FAST + lane] = angB;
        CC[lane] = (v2f){__cosf(0.5f * angA), __cosf(0.5f * angB)};
        SS[lane] = (v2f){__sinf(0.5f * angA), __sinf(0.5f * angB)};
    }

    // ---- paired product state: u[r] = (ampA(r), ampB(r)) ----
    v2f u[64];
    {
        v2f g0[NQ], g1[NQ];
        #pragma unroll
        for (int w = 0; w < NQ; w++) {
            float hA = 0.5f * xaA[w], hB = 0.5f * xaB[w];
            float cA = __cosf(hA), sA = __sinf(hA);
            float cB = __cosf(hB), sB = __sinf(hB);
            const float K = 0.70710678118654752f;
            g0[w] = (v2f){(cA - sA) * K, (cB - sB) * K};
            g1[w] = (v2f){(cA + sA) * K, (cB + sB) * K};
        }
        v2f L = (v2f){1.0f, 1.0f};
        #pragma unroll
        for (int w = 0; w < 6; w++)
            L *= ((lane >> (5 - w)) & 1) ? g1[w] : g0[w];
        u[0] = L;
        #pragma unroll
        for (int w = 6; w < NQ; w++) {
            const int S = 1 << (11 - w);
            #pragma unroll
            for (int r = 0; r < 64; r += 2 * S) {
                u[r + S] = u[r] * g1[w];
                u[r]     = u[r] * g0[w];
            }
        }
    }

    // ---- round-trip addressing (off folded into base pointers) ----
    const int g    = G6(lane);
    const int gp   = g ^ 48;                // partner row (lane^32)
    const int off2 = (lane & 1) * 64;       // float offset of the ^32 col-xor
    const float* s_lo = Xs + g  * PPF + off2;
    const float* s_hi = Xs + g  * PPF + (off2 ^ 64);
    const float* p_lo = Xs + gp * PPF + off2;
    const float* p_hi = Xs + gp * PPF + (off2 ^ 64);
    float* wrow = Xs + lane * PPF;

    // ---- 4 layers; one b128 round trip each, wires fully packed ----
    #pragma unroll 1
    for (int layer = 0; layer < DEPTH; layer++) {
        v2f cc[NQ], ss[NQ];
        #pragma unroll
        for (int w = 0; w < NQ; w++) { cc[w] = CC[layer * NQ + w]; ss[w] = SS[layer * NQ + w]; }
        v2f ss0 = (lane & 32) ? ss[0] : -ss[0];

        // stage write: canonical rows, straight b128
        #pragma unroll
        for (int k = 0; k < 32; k++)
            *(float4*)&wrow[4 * k] =
                (float4){u[2 * k].x, u[2 * k].y, u[2 * k + 1].x, u[2 * k + 1].y};

        // sigma-folded read (self + partner) + fused wire0
        #pragma unroll
        for (int b = 0; b < 16; b++) {
            const int q = b ^ (b >> 1);                      // source block G4(b)
            const float* ps = (q < 8) ? s_lo + 8 * q : s_hi + 8 * (q - 8);
            const float* pq = (q < 8) ? p_lo + 8 * q : p_hi + 8 * (q - 8);
            float4 sa = *(const float4*)ps, sb = *(const float4*)(ps + 4);
            float4 pa = *(const float4*)pq, pb = *(const float4*)(pq + 4);
            v2f w0 = {sa.x, sa.y}, w1 = {sa.z, sa.w}, w2v = {sb.x, sb.y}, w3 = {sb.z, sb.w};
            v2f p0 = {pa.x, pa.y}, p1 = {pa.z, pa.w}, p2v = {pb.x, pb.y}, p3 = {pb.z, pb.w};
            if ((b & 1) == 0) {          // in-block gray map {0,1,3,2}
                u[4 * b + 0] = cc[0] * w0  + ss0 * p0;
                u[4 * b + 1] = cc[0] * w1  + ss0 * p1;
                u[4 * b + 2] = cc[0] * w3  + ss0 * p3;
                u[4 * b + 3] = cc[0] * w2v + ss0 * p2v;
            } else {                     // {2,3,1,0}
                u[4 * b + 0] = cc[0] * w2v + ss0 * p2v;
                u[4 * b + 1] = cc[0] * w3  + ss0 * p3;
                u[4 * b + 2] = cc[0] * w1  + ss0 * p1;
                u[4 * b + 3] = cc[0] * w0  + ss0 * p0;
            }
        }

        // lane-bit wires 1..5 (bits 4..0); swizzle wire first (DS overlap)
        { v2f sv = (lane & 16) ? ss[1] : -ss[1]; lanewire2<4>(u, cc[1], sv); }
        { v2f sv = (lane &  8) ? ss[2] : -ss[2]; lanewire2<3>(u, cc[2], sv); }
        { v2f sv = (lane &  4) ? ss[3] : -ss[3]; lanewire2<2>(u, cc[3], sv); }
        { v2f sv = (lane &  2) ? ss[4] : -ss[4]; lanewire2<1>(u, cc[4], sv); }
        { v2f sv = (lane &  1) ? ss[5] : -ss[5]; lanewire2<0>(u, cc[5], sv); }

        // amp-register wires 6..11 (bits 5..0): packed butterflies
        regwire2<5>(u, cc[6],  ss[6]);
        regwire2<4>(u, cc[7],  ss[7]);
        regwire2<3>(u, cc[8],  ss[8]);
        regwire2<2>(u, cc[9],  ss[9]);
        regwire2<1>(u, cc[10], ss[10]);
        regwire2<0>(u, cc[11], ss[11]);
    }

    // ---- Z expectations folded into readout, both elements packed ----
    float wro[NQ];
    #pragma unroll
    for (int w = 0; w < NQ; w++) wro[w] = W_ro[w];
    float sl = 0.0f;
    #pragma unroll
    for (int w = 0; w < 6; w++)
        sl += ((lane >> (5 - w)) & 1) ? -wro[w] : wro[w];

    v2f tot = (v2f){0.0f, 0.0f};
    v2f pw[6];
    #pragma unroll
    for (int k = 0; k < 6; k++) pw[k] = (v2f){0.0f, 0.0f};
    #pragma unroll
    for (int r = 0; r < 64; r++) {
        v2f p = u[r] * u[r];
        tot += p;
        pw[0] += (r & 32) ? -p : p;
        pw[1] += (r & 16) ? -p : p;
        pw[2] += (r & 8)  ? -p : p;
        pw[3] += (r & 4)  ? -p : p;
        pw[4] += (r & 2)  ? -p : p;
        pw[5] += (r & 1)  ? -p : p;
    }
    v2f y2 = (v2f){sl, sl} * tot;
    #pragma unroll
    for (int k = 0; k < 6; k++) y2 += (v2f){wro[6 + k], wro[6 + k]} * pw[k];
    float yA = y2.x, yB = y2.y;
    #pragma unroll
    for (int m = 32; m >= 1; m >>= 1) {
        yA += __shfl_xor(yA, m, 64);
        yB += __shfl_xor(yB, m, 64);
    }
    if (lane == 0) {
        float br = b_ro[0];
        out_y[eA] = yA + br;
        out_y[eB] = yB + br;
    }
}

extern "C" void kernel_launch(void* const* d_in, const int* in_sizes, int n_in,
                              void* d_out, int out_size, void* d_ws, size_t ws_size,
                              hipStream_t stream) {
    const float* x_t       = (const float*)d_in[0];
    const float* fast_prev = (const float*)d_in[1];
    const float* W_enc     = (const float*)d_in[2];
    const float* b_enc     = (const float*)d_in[3];
    const float* W_upd     = (const float*)d_in[4];
    const float* b_upd     = (const float*)d_in[5];
    const float* W_ro      = (const float*)d_in[6];
    const float* b_ro      = (const float*)d_in[7];
    float* out = (float*)d_out;

    // 1024 blocks x 1 wave, 2 batch elements per wave (packed in v2f)
    fwp_kernel<<<1024, 64, 0, stream>>>(x_t, fast_prev, W_enc, b_enc,
                                        W_upd, b_upd, W_ro, b_ro,
                                        out /*y*/, out + 2048 /*fast_next*/);
}

// Round 4
// 115.273 us; speedup vs baseline: 1.0549x; 1.0176x over previous
//
#include <hip/hip_runtime.h>

// Problem constants
static constexpr int NQ    = 12;
static constexpr int DEPTH = 4;
static constexpr int LAT   = 512;
static constexpr int FAST  = DEPTH * NQ;   // 48
static constexpr float DECAY = 0.9f;

using v2f = __attribute__((ext_vector_type(2))) float;

// r18 KEY CHANGE: no LDS state staging at all. Layout role-swap:
//   amp j = (h<<6) | l ; REGISTER index = h (wires 0..5), LANE = l (wires 6..11).
//   sigma^-1(j): bit_p = j_p ^ j_{p+1} [r13-verified] splits as
//     src_reg  = G6(h)                  (compile-time gray rename, free in SSA)
//     src_lane = G6(l) ^ (h0<<5)        h0 = bit0 of DEST h  -> compile-time
//   so sigma = 64 ds_bpermute with one of TWO precomputed index vectors
//   (idxA = 4*G6(lane), idxB = idxA^128), chosen per-register at compile time.
//   Wires 0..5  = r14's verified v2f-packed register butterflies (ry6).
//   Wires 6..11 = lane exchanges: xor32 bpermute, xor16 ds_swizzle 0x401F,
//     xor8 DPP row_ror:8, xor4 = half_mirror o quad_perm[3,2,1,0],
//     xor2/xor1 quad_perm  [all passed correctness in r16/r17 runs].
// Removes the 8 per-wave LDS round-trip drain walls (160-op bursts vs the
// 4-bit lgkmcnt clamp) that dominated r14's 48us (VALU 32%, DS 28%, rest
// stall). All DS ops are now pipelined single pulls; A/B streams interleaved
// pairwise so each burst's latency hides under the other's math.

__device__ __forceinline__ constexpr int G6(int x)  { return (x ^ (x >> 1)) & 63; }

__device__ __forceinline__ float bperm(int idx, float v){
    return __int_as_float(__builtin_amdgcn_ds_bpermute(idx, __float_as_int(v)));
}
template<int CTRL>
__device__ __forceinline__ float dppf(float x){
    return __int_as_float(__builtin_amdgcn_mov_dpp(__float_as_int(x), CTRL, 0xF, 0xF, false));
}
__device__ __forceinline__ float swz16(float x){
    return __int_as_float(__builtin_amdgcn_ds_swizzle(__float_as_int(x), 0x401F));
}

// ---------------- r14-verified register butterflies (wires 0..5) ----------
template<int S, int B>
__device__ __forceinline__ void bfly_half(float (&v)[64], float c, float s) {
    v2f c2 = {c, c}, s2 = {s, s};
    #pragma unroll
    for (int r0 = B; r0 < B + 32; r0 += 2) {
        if ((r0 & S) == 0) {
            v2f a = {v[r0],     v[r0 + 1]};
            v2f b = {v[r0 + S], v[r0 + S + 1]};
            v2f na = c2 * a - s2 * b;
            v2f nb = s2 * a + c2 * b;
            v[r0]     = na.x;  v[r0 + 1]     = na.y;
            v[r0 + S] = nb.x;  v[r0 + S + 1] = nb.y;
        }
    }
}
template<int B>
__device__ __forceinline__ void bfly1_half(float (&v)[64], float c, float s) {
    v2f cs = {c, s}, nsc = {-s, c};
    #pragma unroll
    for (int r0 = B; r0 < B + 32; r0 += 2) {
        float a = v[r0], b = v[r0 + 1];
        v2f aa = {a, a}, bb = {b, b};
        v2f res = cs * aa + nsc * bb;   // (c*a - s*b, s*a + c*b)
        v[r0]     = res.x;
        v[r0 + 1] = res.y;
    }
}
template<int B>
__device__ __forceinline__ void ry5_half(float (&v)[64], const v2f* cs) {
    bfly_half<16, B>(v, cs[0].x, cs[0].y);
    bfly_half<8,  B>(v, cs[1].x, cs[1].y);
    bfly_half<4,  B>(v, cs[2].x, cs[2].y);
    bfly_half<2,  B>(v, cs[3].x, cs[3].y);
    bfly1_half<B>(v, cs[4].x, cs[4].y);
}
__device__ __forceinline__ void bfly32(float (&v)[64], float c, float s) {
    v2f c2 = {c, c}, s2 = {s, s};
    #pragma unroll
    for (int r0 = 0; r0 < 32; r0 += 2) {
        v2f a = {v[r0],      v[r0 + 1]};
        v2f b = {v[r0 + 32], v[r0 + 33]};
        v2f na = c2 * a - s2 * b;
        v2f nb = s2 * a + c2 * b;
        v[r0]      = na.x;  v[r0 + 1]  = na.y;
        v[r0 + 32] = nb.x;  v[r0 + 33] = nb.y;
    }
}
// wires 0..5: cs[0] = stride-32 (wire0) ... cs[5] = stride-1 (wire5)
__device__ __forceinline__ void ry6(float (&v)[64], const v2f* cs) {
    ry5_half<0>(v, cs + 1);
    ry5_half<32>(v, cs + 1);
    bfly32(v, cs[0].x, cs[0].y);
}

// ---------------- product state (mirror of r2-r13-verified init) ----------
// lane = low 6 amp bits (wires 6..11), reg h = high 6 (wires 0..5)
__device__ __forceinline__ void init_state(float (&v)[64], const float (&xa)[NQ], int lane) {
    float g0[NQ], g1[NQ];
    #pragma unroll
    for (int w = 0; w < NQ; w++) {
        float hh = 0.5f * xa[w];
        float c = __cosf(hh), s = __sinf(hh);
        g0[w] = (c - s) * 0.70710678118654752f;
        g1[w] = (c + s) * 0.70710678118654752f;
    }
    float L = 1.0f;
    #pragma unroll
    for (int w = 6; w < NQ; w++)
        L *= ((lane >> (11 - w)) & 1) ? g1[w] : g0[w];
    v[0] = L;
    #pragma unroll
    for (int w = 0; w < 6; w++) {
        const int S = 32 >> w;             // h bit (5-w)
        #pragma unroll
        for (int r = 0; r < 64; r += 2 * S) {
            v[r + S] = v[r] * g1[w];
            v[r]     = v[r] * g0[w];
        }
    }
}

__global__ __launch_bounds__(64, 1)
void fwp_kernel(const float* __restrict__ x_t,
                const float* __restrict__ fast_prev,
                const float* __restrict__ W_enc,
                const float* __restrict__ b_enc,
                const float* __restrict__ W_upd,
                const float* __restrict__ b_upd,
                const float* __restrict__ W_ro,
                const float* __restrict__ b_ro,
                float* __restrict__ out_y,
                float* __restrict__ out_fast) {
    const int lane = threadIdx.x;          // block = one wave
    const int eA   = 2 * blockIdx.x;
    const int eB   = eA + 1;

    __shared__ __align__(16) float latA[LAT], latB[LAT];     // 4 KB
    __shared__ __align__(8)  v2f   csA[FAST], csB[FAST];     // 768 B

    // ---- x rows (wave-uniform scalar loads, verified r7) ----
    float xaA[NQ], xaB[NQ];
    #pragma unroll
    for (int k = 0; k < NQ; k++) {
        xaA[k] = x_t[eA * NQ + k];
        xaB[k] = x_t[eB * NQ + k];
    }

    // ---- Phase A: lane owns latents j = 8*lane..8*lane+7 (verified r13) ----
    {
        const float4* we = (const float4*)(W_enc + lane * 8 * NQ);  // 8 rows, 384 B
        float4 be0 = *(const float4*)&b_enc[8 * lane];
        float4 be1 = *(const float4*)&b_enc[8 * lane + 4];
        float be[8] = {be0.x, be0.y, be0.z, be0.w, be1.x, be1.y, be1.z, be1.w};
        float lA[8], lB[8];
        #pragma unroll
        for (int t = 0; t < 8; t++) {
            float4 a0 = we[3 * t], a1 = we[3 * t + 1], a2 = we[3 * t + 2];
            float sA = be[t]
                + a0.x * xaA[0] + a0.y * xaA[1] + a0.z * xaA[2]  + a0.w * xaA[3]
                + a1.x * xaA[4] + a1.y * xaA[5] + a1.z * xaA[6]  + a1.w * xaA[7]
                + a2.x * xaA[8] + a2.y * xaA[9] + a2.z * xaA[10] + a2.w * xaA[11];
            float sB = be[t]
                + a0.x * xaB[0] + a0.y * xaB[1] + a0.z * xaB[2]  + a0.w * xaB[3]
                + a1.x * xaB[4] + a1.y * xaB[5] + a1.z * xaB[6]  + a1.w * xaB[7]
                + a2.x * xaB[8] + a2.y * xaB[9] + a2.z * xaB[10] + a2.w * xaB[11];
            lA[t] = tanhf(sA);
            lB[t] = tanhf(sB);
        }
        *(float4*)&latA[8 * lane]     = (float4){lA[0], lA[1], lA[2], lA[3]};
        *(float4*)&latA[8 * lane + 4] = (float4){lA[4], lA[5], lA[6], lA[7]};
        *(float4*)&latB[8 * lane]     = (float4){lB[0], lB[1], lB[2], lB[3]};
        *(float4*)&latB[8 * lane + 4] = (float4){lB[4], lB[5], lB[6], lB[7]};
    }

    // ---- Phase B: 48 angles per element; W_upd row loaded once ----
    if (lane < FAST) {
        const float4* wr = (const float4*)(W_upd + lane * LAT);
        const float4* la = (const float4*)(latA);
        const float4* lb = (const float4*)(latB);
        float base = b_upd[lane];
        float sA = base, sB = base;
        #pragma unroll 8
        for (int j = 0; j < LAT / 4; j++) {
            float4 w4 = wr[j];
            float4 a4 = la[j];   // uniform -> broadcast
            float4 b4 = lb[j];
            sA += w4.x * a4.x + w4.y * a4.y + w4.z * a4.z + w4.w * a4.w;
            sB += w4.x * b4.x + w4.y * b4.y + w4.z * b4.z + w4.w * b4.w;
        }
        float angA = DECAY * fast_prev[eA * FAST + lane] + sA;
        float angB = DECAY * fast_prev[eB * FAST + lane] + sB;
        out_fast[eA * FAST + lane] = angA;
        out_fast[eB * FAST + lane] = angB;
        csA[lane] = (v2f){__cosf(0.5f * angA), __sinf(0.5f * angA)};
        csB[lane] = (v2f){__cosf(0.5f * angB), __sinf(0.5f * angB)};
    }

    // ---- product states (registers only; never staged to LDS) ----
    float xA[64], xB[64];
    init_state(xA, xaA, lane);
    init_state(xB, xaB, lane);

    // sigma lane-pull index vectors (bytes)
    const int idxA  = G6(lane) * 4;          // h0 = 0
    const int idxB  = idxA ^ 128;            // h0 = 1  (^32 lanes)
    const int idx32 = (lane * 4) ^ 128;      // wire6 partner (lane^32)

    // ---- 4 layers; zero LDS round trips ----
    #pragma unroll 1
    for (int layer = 0; layer < DEPTH; layer++) {
        v2f cA[NQ], cB[NQ];
        #pragma unroll
        for (int w = 0; w < NQ; w++) {
            cA[w] = csA[layer * NQ + w];
            cB[w] = csB[layer * NQ + w];
        }

        // ---- sigma: t[h] = x[G6(h)] pulled from lane G6(l)^(h0<<5) ----
        float tA[64], tB[64];
        #pragma unroll
        for (int h = 0; h < 64; h++) {
            const int g   = G6(h);
            const int idx = (h & 1) ? idxB : idxA;   // h0 = bit0 of dest h
            tA[h] = bperm(idx, xA[g]);
            tB[h] = bperm(idx, xB[g]);
        }
        #pragma unroll
        for (int h = 0; h < 64; h++) { xA[h] = tA[h]; xB[h] = tB[h]; }  // SSA rename

        // ---- wire6: lane bit5 (xor32 via bpermute) ----
        {
            float sa = (lane & 32) ? cA[6].y : -cA[6].y;
            float sb = (lane & 32) ? cB[6].y : -cB[6].y;
            #pragma unroll
            for (int h = 0; h < 64; h++) {
                float pa = bperm(idx32, xA[h]);
                float pb = bperm(idx32, xB[h]);
                xA[h] = __builtin_fmaf(cA[6].x, xA[h], sa * pa);
                xB[h] = __builtin_fmaf(cB[6].x, xB[h], sb * pb);
            }
        }
        // ---- wire7: xor16 via ds_swizzle ----
        {
            float sa = (lane & 16) ? cA[7].y : -cA[7].y;
            float sb = (lane & 16) ? cB[7].y : -cB[7].y;
            #pragma unroll
            for (int h = 0; h < 64; h++) {
                float pa = swz16(xA[h]);
                float pb = swz16(xB[h]);
                xA[h] = __builtin_fmaf(cA[7].x, xA[h], sa * pa);
                xB[h] = __builtin_fmaf(cB[7].x, xB[h], sb * pb);
            }
        }
        // ---- wire8: xor8 via DPP row_ror:8 ----
        {
            float sa = (lane & 8) ? cA[8].y : -cA[8].y;
            float sb = (lane & 8) ? cB[8].y : -cB[8].y;
            #pragma unroll
            for (int h = 0; h < 64; h++) {
                float pa = dppf<0x128>(xA[h]);
                float pb = dppf<0x128>(xB[h]);
                xA[h] = __builtin_fmaf(cA[8].x, xA[h], sa * pa);
                xB[h] = __builtin_fmaf(cB[8].x, xB[h], sb * pb);
            }
        }
        // ---- wire9: xor4 = half_mirror o quad_perm[3,2,1,0] ----
        {
            float sa = (lane & 4) ? cA[9].y : -cA[9].y;
            float sb = (lane & 4) ? cB[9].y : -cB[9].y;
            #pragma unroll
            for (int h = 0; h < 64; h++) {
                float pa = dppf<0x141>(dppf<0x1B>(xA[h]));
                float pb = dppf<0x141>(dppf<0x1B>(xB[h]));
                xA[h] = __builtin_fmaf(cA[9].x, xA[h], sa * pa);
                xB[h] = __builtin_fmaf(cB[9].x, xB[h], sb * pb);
            }
        }
        // ---- wire10: xor2 quad_perm[2,3,0,1] ----
        {
            float sa = (lane & 2) ? cA[10].y : -cA[10].y;
            float sb = (lane & 2) ? cB[10].y : -cB[10].y;
            #pragma unroll
            for (int h = 0; h < 64; h++) {
                float pa = dppf<0x4E>(xA[h]);
                float pb = dppf<0x4E>(xB[h]);
                xA[h] = __builtin_fmaf(cA[10].x, xA[h], sa * pa);
                xB[h] = __builtin_fmaf(cB[10].x, xB[h], sb * pb);
            }
        }
        // ---- wire11: xor1 quad_perm[1,0,3,2] ----
        {
            float sa = (lane & 1) ? cA[11].y : -cA[11].y;
            float sb = (lane & 1) ? cB[11].y : -cB[11].y;
            #pragma unroll
            for (int h = 0; h < 64; h++) {
                float pa = dppf<0xB1>(xA[h]);
                float pb = dppf<0xB1>(xB[h]);
                xA[h] = __builtin_fmaf(cA[11].x, xA[h], sa * pa);
                xB[h] = __builtin_fmaf(cB[11].x, xB[h], sb * pb);
            }
        }
        // ---- wires 0..5: register butterflies (r14-verified ry6) ----
        ry6(xA, cA);
        ry6(xB, cB);
    }

    // ---- Z expectations folded into readout (mirror of verified r9) ----
    float wro[NQ];
    #pragma unroll
    for (int w = 0; w < NQ; w++) wro[w] = W_ro[w];
    // lane-resident wires 6..11: bit = lane >> (11-w)
    float sl = 0.0f;
    #pragma unroll
    for (int w = 6; w < NQ; w++)
        sl += ((lane >> (11 - w)) & 1) ? -wro[w] : wro[w];

    float totA = 0.0f, pwA[6] = {0,0,0,0,0,0};
    float totB = 0.0f, pwB[6] = {0,0,0,0,0,0};
    #pragma unroll
    for (int r = 0; r < 64; r++) {
        float pA = xA[r] * xA[r];
        float pB = xB[r] * xB[r];
        totA += pA;  totB += pB;
        pwA[0] += (r & 32) ? -pA : pA;  pwB[0] += (r & 32) ? -pB : pB;  // wire0
        pwA[1] += (r & 16) ? -pA : pA;  pwB[1] += (r & 16) ? -pB : pB;  // wire1
        pwA[2] += (r & 8)  ? -pA : pA;  pwB[2] += (r & 8)  ? -pB : pB;  // wire2
        pwA[3] += (r & 4)  ? -pA : pA;  pwB[3] += (r & 4)  ? -pB : pB;  // wire3
        pwA[4] += (r & 2)  ? -pA : pA;  pwB[4] += (r & 2)  ? -pB : pB;  // wire4
        pwA[5] += (r & 1)  ? -pA : pA;  pwB[5] += (r & 1)  ? -pB : pB;  // wire5
    }
    float yA = sl * totA, yB = sl * totB;
    #pragma unroll
    for (int k = 0; k < 6; k++) {
        yA += wro[k] * pwA[k];
        yB += wro[k] * pwB[k];
    }
    #pragma unroll
    for (int m = 32; m >= 1; m >>= 1) {
        yA += __shfl_xor(yA, m, 64);
        yB += __shfl_xor(yB, m, 64);
    }
    if (lane == 0) {
        float br = b_ro[0];
        out_y[eA] = yA + br;
        out_y[eB] = yB + br;
    }
}

extern "C" void kernel_launch(void* const* d_in, const int* in_sizes, int n_in,
                              void* d_out, int out_size, void* d_ws, size_t ws_size,
                              hipStream_t stream) {
    const float* x_t       = (const float*)d_in[0];
    const float* fast_prev = (const float*)d_in[1];
    const float* W_enc     = (const float*)d_in[2];
    const float* b_enc     = (const float*)d_in[3];
    const float* W_upd     = (const float*)d_in[4];
    const float* b_upd     = (const float*)d_in[5];
    const float* W_ro      = (const float*)d_in[6];
    const float* b_ro      = (const float*)d_in[7];
    float* out = (float*)d_out;

    // 1024 blocks x 1 wave, 2 batch elements per wave
    fwp_kernel<<<1024, 64, 0, stream>>>(x_t, fast_prev, W_enc, b_enc,
                                        W_upd, b_upd, W_ro, b_ro,
                                        out /*y*/, out + 2048 /*fast_next*/);
}

// Round 5
// 114.292 us; speedup vs baseline: 1.0639x; 1.0086x over previous
//
#include <hip/hip_runtime.h>

// Problem constants
static constexpr int NQ    = 12;
static constexpr int DEPTH = 4;
static constexpr int LAT   = 512;
static constexpr int FAST  = DEPTH * NQ;   // 48
static constexpr float DECAY = 0.9f;

using v2f = __attribute__((ext_vector_type(2))) float;

// r19: r18's verified structure (layout role-swap: reg h = wires 0..5,
// lane l = wires 6..11; sigma = G6 reg-rename + bperm lane pull with
// idx = (h&1)? idxB : idxA  [r18 HW-verified]) with three changes:
//  1. A,B packed per-amp in v2f -> every wire's math is packed ops
//     (halves VALU instruction count vs r18's scalar A/B streams).
//  2. wires 6/7 (xor32/xor16) via v_permlane{32,16}_swap_b32 (VALU,
//     m255: permlane 1.20x vs ds_bpermute) in DIRECTION-PROOF sum form:
//     swap(x,x) yields two regs whose SUM = x + x^M under either
//     operand-order semantic; out = (c-s')*x + s'*(x + x^M) == c*x + s'*x^M.
//     DS per layer drops 384 -> 128 (one DS stage: sigma only).
//  3. sigma applied in-place along G6's register cycles (2 fix + one
//     2-cycle + three 4-cycles + six 8-cycles) -> no 128-float temp spike.

__device__ __forceinline__ constexpr int G6(int x){ return (x ^ (x >> 1)) & 63; }

__device__ __forceinline__ float bperm(int idx, float v){
    return __int_as_float(__builtin_amdgcn_ds_bpermute(idx, __float_as_int(v)));
}
template<int CTRL>
__device__ __forceinline__ float dppf(float x){
    return __int_as_float(__builtin_amdgcn_mov_dpp(__float_as_int(x), CTRL, 0xF, 0xF, false));
}
template<int CTRL>
__device__ __forceinline__ v2f dpp2(v2f v){ return (v2f){dppf<CTRL>(v.x), dppf<CTRL>(v.y)}; }

// x[l] + x[l^32]  (direction-proof: both swap outputs sum to lo+hi halves)
__device__ __forceinline__ float xsum32(float x){
    float a = x, b = x;
    asm("v_permlane32_swap_b32 %0, %1" : "+v"(a), "+v"(b));
    return a + b;
}
// x[l] + x[l^16]
__device__ __forceinline__ float xsum16(float x){
    float a = x, b = x;
    asm("v_permlane16_swap_b32 %0, %1" : "+v"(a), "+v"(b));
    return a + b;
}

// register butterfly, wire stride S (amp bit), packed (A,B)
template<int S>
__device__ __forceinline__ void rw(v2f (&u)[64], v2f cc, v2f ss){
    #pragma unroll
    for (int r = 0; r < 64; r++){
        if (!(r & S)){
            v2f a = u[r], b = u[r | S];
            u[r]     = cc * a - ss * b;
            u[r | S] = ss * a + cc * b;
        }
    }
}

__global__ __launch_bounds__(64, 1)
void fwp_kernel(const float* __restrict__ x_t,
                const float* __restrict__ fast_prev,
                const float* __restrict__ W_enc,
                const float* __restrict__ b_enc,
                const float* __restrict__ W_upd,
                const float* __restrict__ b_upd,
                const float* __restrict__ W_ro,
                const float* __restrict__ b_ro,
                float* __restrict__ out_y,
                float* __restrict__ out_fast) {
    const int lane = threadIdx.x;          // block = one wave
    const int eA   = 2 * blockIdx.x;
    const int eB   = eA + 1;

    __shared__ __align__(16) float latA[LAT], latB[LAT];   // 4 KB
    __shared__ __align__(8)  v2f CC[FAST], SS[FAST];       // zipped (A,B) angles

    // ---- x rows (wave-uniform scalar loads, verified r7) ----
    float xaA[NQ], xaB[NQ];
    #pragma unroll
    for (int k = 0; k < NQ; k++) {
        xaA[k] = x_t[eA * NQ + k];
        xaB[k] = x_t[eB * NQ + k];
    }

    // ---- Phase A: lane owns latents j = 8*lane..8*lane+7 (verified r13) ----
    {
        const float4* we = (const float4*)(W_enc + lane * 8 * NQ);  // 8 rows, 384 B
        float4 be0 = *(const float4*)&b_enc[8 * lane];
        float4 be1 = *(const float4*)&b_enc[8 * lane + 4];
        float be[8] = {be0.x, be0.y, be0.z, be0.w, be1.x, be1.y, be1.z, be1.w};
        float lA[8], lB[8];
        #pragma unroll
        for (int t = 0; t < 8; t++) {
            float4 a0 = we[3 * t], a1 = we[3 * t + 1], a2 = we[3 * t + 2];
            float sA = be[t]
                + a0.x * xaA[0] + a0.y * xaA[1] + a0.z * xaA[2]  + a0.w * xaA[3]
                + a1.x * xaA[4] + a1.y * xaA[5] + a1.z * xaA[6]  + a1.w * xaA[7]
                + a2.x * xaA[8] + a2.y * xaA[9] + a2.z * xaA[10] + a2.w * xaA[11];
            float sB = be[t]
                + a0.x * xaB[0] + a0.y * xaB[1] + a0.z * xaB[2]  + a0.w * xaB[3]
                + a1.x * xaB[4] + a1.y * xaB[5] + a1.z * xaB[6]  + a1.w * xaB[7]
                + a2.x * xaB[8] + a2.y * xaB[9] + a2.z * xaB[10] + a2.w * xaB[11];
            lA[t] = tanhf(sA);
            lB[t] = tanhf(sB);
        }
        *(float4*)&latA[8 * lane]     = (float4){lA[0], lA[1], lA[2], lA[3]};
        *(float4*)&latA[8 * lane + 4] = (float4){lA[4], lA[5], lA[6], lA[7]};
        *(float4*)&latB[8 * lane]     = (float4){lB[0], lB[1], lB[2], lB[3]};
        *(float4*)&latB[8 * lane + 4] = (float4){lB[4], lB[5], lB[6], lB[7]};
    }

    // ---- Phase B: 48 angles per element; W_upd row loaded once ----
    if (lane < FAST) {
        const float4* wr = (const float4*)(W_upd + lane * LAT);
        const float4* la = (const float4*)(latA);
        const float4* lb = (const float4*)(latB);
        float base = b_upd[lane];
        float sA = base, sB = base;
        #pragma unroll 8
        for (int j = 0; j < LAT / 4; j++) {
            float4 w4 = wr[j];
            float4 a4 = la[j];   // uniform -> broadcast
            float4 b4 = lb[j];
            sA += w4.x * a4.x + w4.y * a4.y + w4.z * a4.z + w4.w * a4.w;
            sB += w4.x * b4.x + w4.y * b4.y + w4.z * b4.z + w4.w * b4.w;
        }
        float angA = DECAY * fast_prev[eA * FAST + lane] + sA;
        float angB = DECAY * fast_prev[eB * FAST + lane] + sB;
        out_fast[eA * FAST + lane] = angA;
        out_fast[eB * FAST + lane] = angB;
        CC[lane] = (v2f){__cosf(0.5f * angA), __cosf(0.5f * angB)};
        SS[lane] = (v2f){__sinf(0.5f * angA), __sinf(0.5f * angB)};
    }

    // ---- packed product state: u[h] = (ampA, ampB), reg h = wires 0..5 ----
    v2f u[64];
    {
        v2f g0[NQ], g1[NQ];
        #pragma unroll
        for (int w = 0; w < NQ; w++) {
            float hA = 0.5f * xaA[w], hB = 0.5f * xaB[w];
            float cA = __cosf(hA), sA = __sinf(hA);
            float cB = __cosf(hB), sB = __sinf(hB);
            const float K = 0.70710678118654752f;
            g0[w] = (v2f){(cA - sA) * K, (cB - sB) * K};
            g1[w] = (v2f){(cA + sA) * K, (cB + sB) * K};
        }
        v2f L = (v2f){1.0f, 1.0f};
        #pragma unroll
        for (int w = 6; w < NQ; w++)
            L *= ((lane >> (11 - w)) & 1) ? g1[w] : g0[w];
        u[0] = L;
        #pragma unroll
        for (int w = 0; w < 6; w++) {
            const int S = 32 >> w;
            #pragma unroll
            for (int r = 0; r < 64; r += 2 * S) {
                u[r + S] = u[r] * g1[w];
                u[r]     = u[r] * g0[w];
            }
        }
    }

    // sigma lane-pull index vectors (bytes) [r18-verified]
    const int idxA = G6(lane) * 4;           // h0 = 0
    const int idxB = idxA ^ 128;             // h0 = 1  (^32 lanes)

    // in-place sigma step: u[h] = bperm(idx(h), src), src = old u[G6(h)]
    #define SIG1(h, src) { const int idx_ = ((h) & 1) ? idxB : idxA; \
        u[h] = (v2f){ bperm(idx_, (src).x), bperm(idx_, (src).y) }; }

    // ---- 4 layers ----
    #pragma unroll 1
    for (int layer = 0; layer < DEPTH; layer++) {
        v2f cc[NQ], ss[NQ];
        #pragma unroll
        for (int w = 0; w < NQ; w++) { cc[w] = CC[layer * NQ + w]; ss[w] = SS[layer * NQ + w]; }

        // -------- sigma: in-place along G6 register cycles --------
        SIG1(0, u[0]);  SIG1(1, u[1]);
        { v2f t = u[2]; SIG1(2, u[3]); SIG1(3, t); }
        { v2f t = u[4]; SIG1(4, u[6]);  SIG1(6, u[5]);  SIG1(5, u[7]);  SIG1(7, t); }
        { v2f t = u[8]; SIG1(8, u[12]); SIG1(12, u[10]); SIG1(10, u[15]); SIG1(15, t); }
        { v2f t = u[9]; SIG1(9, u[13]); SIG1(13, u[11]); SIG1(11, u[14]); SIG1(14, t); }
        { v2f t = u[16]; SIG1(16, u[24]); SIG1(24, u[20]); SIG1(20, u[30]); SIG1(30, u[17]);
                         SIG1(17, u[25]); SIG1(25, u[21]); SIG1(21, u[31]); SIG1(31, t); }
        { v2f t = u[18]; SIG1(18, u[27]); SIG1(27, u[22]); SIG1(22, u[29]); SIG1(29, u[19]);
                         SIG1(19, u[26]); SIG1(26, u[23]); SIG1(23, u[28]); SIG1(28, t); }
        { v2f t = u[32]; SIG1(32, u[48]); SIG1(48, u[40]); SIG1(40, u[60]); SIG1(60, u[34]);
                         SIG1(34, u[51]); SIG1(51, u[42]); SIG1(42, u[63]); SIG1(63, t); }
        { v2f t = u[33]; SIG1(33, u[49]); SIG1(49, u[41]); SIG1(41, u[61]); SIG1(61, u[35]);
                         SIG1(35, u[50]); SIG1(50, u[43]); SIG1(43, u[62]); SIG1(62, t); }
        { v2f t = u[36]; SIG1(36, u[54]); SIG1(54, u[45]); SIG1(45, u[59]); SIG1(59, u[38]);
                         SIG1(38, u[53]); SIG1(53, u[47]); SIG1(47, u[56]); SIG1(56, t); }
        { v2f t = u[37]; SIG1(37, u[55]); SIG1(55, u[44]); SIG1(44, u[58]); SIG1(58, u[39]);
                         SIG1(39, u[52]); SIG1(52, u[46]); SIG1(46, u[57]); SIG1(57, t); }

        // -------- wire6: lane bit5 (xor32 via permlane32 sum form) --------
        {
            v2f sv = (lane & 32) ? ss[6] : -ss[6];
            v2f cm = cc[6] - sv;
            #pragma unroll
            for (int h = 0; h < 64; h++) {
                v2f s2 = (v2f){ xsum32(u[h].x), xsum32(u[h].y) };
                u[h] = cm * u[h] + sv * s2;
            }
        }
        // -------- wire7: lane bit4 (xor16 via permlane16 sum form) --------
        {
            v2f sv = (lane & 16) ? ss[7] : -ss[7];
            v2f cm = cc[7] - sv;
            #pragma unroll
            for (int h = 0; h < 64; h++) {
                v2f s2 = (v2f){ xsum16(u[h].x), xsum16(u[h].y) };
                u[h] = cm * u[h] + sv * s2;
            }
        }
        // -------- wire8: xor8 via DPP row_ror:8 [verified] --------
        {
            v2f sv = (lane & 8) ? ss[8] : -ss[8];
            #pragma unroll
            for (int h = 0; h < 64; h++) {
                v2f p = dpp2<0x128>(u[h]);
                u[h] = cc[8] * u[h] + sv * p;
            }
        }
        // -------- wire9: xor4 = half_mirror o quad_perm[3,2,1,0] [verified] --------
        {
            v2f sv = (lane & 4) ? ss[9] : -ss[9];
            #pragma unroll
            for (int h = 0; h < 64; h++) {
                v2f p = dpp2<0x141>(dpp2<0x1B>(u[h]));
                u[h] = cc[9] * u[h] + sv * p;
            }
        }
        // -------- wire10: xor2 quad_perm[2,3,0,1] [verified] --------
        {
            v2f sv = (lane & 2) ? ss[10] : -ss[10];
            #pragma unroll
            for (int h = 0; h < 64; h++) {
                v2f p = dpp2<0x4E>(u[h]);
                u[h] = cc[10] * u[h] + sv * p;
            }
        }
        // -------- wire11: xor1 quad_perm[1,0,3,2] [verified] --------
        {
            v2f sv = (lane & 1) ? ss[11] : -ss[11];
            #pragma unroll
            for (int h = 0; h < 64; h++) {
                v2f p = dpp2<0xB1>(u[h]);
                u[h] = cc[11] * u[h] + sv * p;
            }
        }
        // -------- wires 0..5: packed register butterflies --------
        rw<32>(u, cc[0], ss[0]);
        rw<16>(u, cc[1], ss[1]);
        rw<8> (u, cc[2], ss[2]);
        rw<4> (u, cc[3], ss[3]);
        rw<2> (u, cc[4], ss[4]);
        rw<1> (u, cc[5], ss[5]);
    }
    #undef SIG1

    // ---- Z expectations folded into readout (r18-verified mapping) ----
    float wro[NQ];
    #pragma unroll
    for (int w = 0; w < NQ; w++) wro[w] = W_ro[w];
    float sl = 0.0f;
    #pragma unroll
    for (int w = 6; w < NQ; w++)
        sl += ((lane >> (11 - w)) & 1) ? -wro[w] : wro[w];

    v2f tot = (v2f){0.0f, 0.0f};
    v2f pw[6];
    #pragma unroll
    for (int k = 0; k < 6; k++) pw[k] = (v2f){0.0f, 0.0f};
    #pragma unroll
    for (int r = 0; r < 64; r++) {
        v2f p = u[r] * u[r];
        tot += p;
        pw[0] += (r & 32) ? -p : p;   // wire0 (reg bit5)
        pw[1] += (r & 16) ? -p : p;
        pw[2] += (r & 8)  ? -p : p;
        pw[3] += (r & 4)  ? -p : p;
        pw[4] += (r & 2)  ? -p : p;
        pw[5] += (r & 1)  ? -p : p;   // wire5 (reg bit0)
    }
    v2f y2 = (v2f){sl, sl} * tot;
    #pragma unroll
    for (int k = 0; k < 6; k++) y2 += (v2f){wro[k], wro[k]} * pw[k];
    float yA = y2.x, yB = y2.y;
    #pragma unroll
    for (int m = 32; m >= 1; m >>= 1) {
        yA += __shfl_xor(yA, m, 64);
        yB += __shfl_xor(yB, m, 64);
    }
    if (lane == 0) {
        float br = b_ro[0];
        out_y[eA] = yA + br;
        out_y[eB] = yB + br;
    }
}

extern "C" void kernel_launch(void* const* d_in, const int* in_sizes, int n_in,
                              void* d_out, int out_size, void* d_ws, size_t ws_size,
                              hipStream_t stream) {
    const float* x_t       = (const float*)d_in[0];
    const float* fast_prev = (const float*)d_in[1];
    const float* W_enc     = (const float*)d_in[2];
    const float* b_enc     = (const float*)d_in[3];
    const float* W_upd     = (const float*)d_in[4];
    const float* b_upd     = (const float*)d_in[5];
    const float* W_ro      = (const float*)d_in[6];
    const float* b_ro      = (const float*)d_in[7];
    float* out = (float*)d_out;

    // 1024 blocks x 1 wave, 2 batch elements per wave (packed in v2f)
    fwp_kernel<<<1024, 64, 0, stream>>>(x_t, fast_prev, W_enc, b_enc,
                                        W_upd, b_upd, W_ro, b_ro,
                                        out /*y*/, out + 2048 /*fast_next*/);
}